// Round 5
// baseline (102.592 us; speedup 1.0000x reference)
//
#include <hip/hip_runtime.h>

// X [B=8, L=4096, D=1024] fp32.  O = (L*X - colsum_over_L) / (L-1).
constexpr int Bn = 8;
constexpr int Ln = 4096;
constexpr int Dn = 1024;

constexpr int TD  = 16;          // d-columns per block -> 64 tiles/batch, 512 blocks (2/CU)
constexpr int NT  = 1024;        // threads per block (16 waves)
constexpr int QPB = TD / 4;      // 4 float4-quads span one row of the tile
constexpr int RPI = NT / QPB;    // 256 rows covered per loop iteration
constexpr int NIT = Ln / RPI;    // 16 iterations over L
constexpr int NW  = NT / 64;     // 16 waves

typedef float f32x4 __attribute__((ext_vector_type(4)));

__global__ __launch_bounds__(NT) void ordering_fused_kernel(
    const float* __restrict__ X, float* __restrict__ O) {
    const int tid  = threadIdx.x;
    const int lane = tid & 63;
    const int w    = tid >> 6;           // wave id 0..15
    const int b    = blockIdx.x >> 6;    // / 64 tiles
    const int tile = blockIdx.x & 63;
    const int d0   = tile * TD;
    const int q    = tid & (QPB - 1);    // float4-quad within the 16-col tile
    const int g    = tid >> 2;           // row group 0..255

    const size_t base = (size_t)b * Ln * Dn + (size_t)d0 + (size_t)q * 4;

    // ---- Phase 1: column partial sums over L (4 independent accumulators) ----
    f32x4 a0 = (f32x4)0.f, a1 = (f32x4)0.f, a2 = (f32x4)0.f, a3 = (f32x4)0.f;
#pragma unroll
    for (int it = 0; it < NIT; it += 4) {
        const f32x4 v0 = *reinterpret_cast<const f32x4*>(X + base + (size_t)((it+0)*RPI + g) * Dn);
        const f32x4 v1 = *reinterpret_cast<const f32x4*>(X + base + (size_t)((it+1)*RPI + g) * Dn);
        const f32x4 v2 = *reinterpret_cast<const f32x4*>(X + base + (size_t)((it+2)*RPI + g) * Dn);
        const f32x4 v3 = *reinterpret_cast<const f32x4*>(X + base + (size_t)((it+3)*RPI + g) * Dn);
        a0 += v0; a1 += v1; a2 += v2; a3 += v3;
    }
    f32x4 acc = (a0 + a1) + (a2 + a3);

    // ---- Wave-level butterfly over the 16 row-groups within each wave ----
    // lane = q + 4*(group-within-wave); xor masks 4,8,16,32 sum the groups.
#pragma unroll
    for (int m = QPB; m <= 32; m <<= 1) {
        f32x4 o;
        o.x = __shfl_xor(acc.x, m);
        o.y = __shfl_xor(acc.y, m);
        o.z = __shfl_xor(acc.z, m);
        o.w = __shfl_xor(acc.w, m);
        acc += o;
    }

    // ---- Cross-wave: 16 waves x 4 quads, one barrier, fixed-order sum ----
    __shared__ f32x4 red[NW * QPB];   // 1 KiB
    if (lane < QPB) red[w * QPB + q] = acc;
    __syncthreads();
    f32x4 tot = (f32x4)0.f;
#pragma unroll
    for (int ww = 0; ww < NW; ++ww) {
        tot += red[ww * QPB + q];   // broadcast read per q
    }

    // ---- Phase 2: O = (L*x - tot)/(L-1); X re-read hits L2/L3 ----
    const float Lf  = (float)Ln;
    const float inv = 1.0f / (float)(Ln - 1);
#pragma unroll 8
    for (int it = 0; it < NIT; ++it) {
        const size_t off = base + (size_t)(it * RPI + g) * Dn;
        const f32x4 v = *reinterpret_cast<const f32x4*>(X + off);
        *reinterpret_cast<f32x4*>(O + off) = (Lf * v - tot) * inv;
    }
}

extern "C" void kernel_launch(void* const* d_in, const int* in_sizes, int n_in,
                              void* d_out, int out_size, void* d_ws, size_t ws_size,
                              hipStream_t stream) {
    (void)in_sizes; (void)n_in; (void)d_ws; (void)ws_size; (void)out_size;
    const float* X = (const float*)d_in[0];
    float* O = (float*)d_out;
    const int grid = Bn * (Dn / TD);   // 512 blocks = 2 per CU
    ordering_fused_kernel<<<grid, NT, 0, stream>>>(X, O);
}

// Round 6
// 67.074 us; speedup vs baseline: 1.5295x; 1.5295x over previous
//
#include <hip/hip_runtime.h>

// X [B=8, L=4096, D=1024] fp32.  O = (L*X - colsum_over_L) / (L-1).
// Register-staged: X is read from HBM exactly once, held in VGPRs across the
// block reduce, and O is written straight from registers. 262 MB compulsory
// traffic, no dependence on L2/L3 keeping X alive, no nontemporal stores.
constexpr int Bn = 8;
constexpr int Ln = 4096;
constexpr int Dn = 1024;

constexpr int TD  = 16;          // d-columns per block -> 64 tiles/batch, 512 blocks
constexpr int NT  = 1024;        // threads per block (16 waves) -> 1 block/CU
constexpr int QPB = TD / 4;      // 4 float4-quads span one row of the tile
constexpr int RPI = NT / QPB;    // 256 rows covered per loop iteration
constexpr int NIT = Ln / RPI;    // 16 iterations over L  -> 16 f32x4 staged/thread
constexpr int NW  = NT / 64;     // 16 waves

typedef float f32x4 __attribute__((ext_vector_type(4)));

__global__ __launch_bounds__(NT) void ordering_regstage_kernel(
    const float* __restrict__ X, float* __restrict__ O) {
    const int tid  = threadIdx.x;
    const int lane = tid & 63;
    const int w    = tid >> 6;           // wave id 0..15
    const int b    = blockIdx.x >> 6;    // / 64 tiles
    const int tile = blockIdx.x & 63;
    const int d0   = tile * TD;
    const int q    = tid & (QPB - 1);    // float4-quad within the 16-col tile
    const int g    = tid >> 2;           // row group 0..255

    const size_t base = (size_t)b * Ln * Dn + (size_t)d0 + (size_t)q * 4;
    constexpr size_t STRIDE = (size_t)RPI * Dn;   // elements between iterations

    // ---- Phase 1: load the whole slab into registers, accumulate colsums ----
    f32x4 v[NIT];
#pragma unroll
    for (int it = 0; it < NIT; ++it) {
        v[it] = *reinterpret_cast<const f32x4*>(X + base + (size_t)g * Dn + it * STRIDE);
    }
    f32x4 a0 = (f32x4)0.f, a1 = (f32x4)0.f, a2 = (f32x4)0.f, a3 = (f32x4)0.f;
#pragma unroll
    for (int it = 0; it < NIT; it += 4) {
        a0 += v[it + 0];
        a1 += v[it + 1];
        a2 += v[it + 2];
        a3 += v[it + 3];
    }
    f32x4 acc = (a0 + a1) + (a2 + a3);

    // ---- Wave-level butterfly over the 16 row-groups within each wave ----
    // lane = q + 4*(group-within-wave); xor masks 4,8,16,32 sum the groups.
#pragma unroll
    for (int m = QPB; m <= 32; m <<= 1) {
        f32x4 o;
        o.x = __shfl_xor(acc.x, m);
        o.y = __shfl_xor(acc.y, m);
        o.z = __shfl_xor(acc.z, m);
        o.w = __shfl_xor(acc.w, m);
        acc += o;
    }

    // ---- Cross-wave: 16 waves x 4 quads, one barrier, fixed-order sum ----
    __shared__ f32x4 red[NW * QPB];   // 1 KiB
    if (lane < QPB) red[w * QPB + q] = acc;
    __syncthreads();
    f32x4 tot = (f32x4)0.f;
#pragma unroll
    for (int ww = 0; ww < NW; ++ww) {
        tot += red[ww * QPB + q];   // broadcast read per q
    }

    // ---- Phase 2: O = (L*x - tot)/(L-1) straight from registers ----
    const float Lf  = (float)Ln;
    const float inv = 1.0f / (float)(Ln - 1);
#pragma unroll
    for (int it = 0; it < NIT; ++it) {
        const size_t off = base + (size_t)g * Dn + it * STRIDE;
        *reinterpret_cast<f32x4*>(O + off) = (Lf * v[it] - tot) * inv;
    }
}

extern "C" void kernel_launch(void* const* d_in, const int* in_sizes, int n_in,
                              void* d_out, int out_size, void* d_ws, size_t ws_size,
                              hipStream_t stream) {
    (void)in_sizes; (void)n_in; (void)d_ws; (void)ws_size; (void)out_size;
    const float* X = (const float*)d_in[0];
    float* O = (float*)d_out;
    const int grid = Bn * (Dn / TD);   // 512 blocks (two waves of 256 CUs)
    ordering_regstage_kernel<<<grid, NT, 0, stream>>>(X, O);
}